// Round 3
// baseline (383.280 us; speedup 1.0000x reference)
//
#include <hip/hip_runtime.h>
#include <math.h>
#include <stdint.h>

#define S_    2048
#define SCALE_ 0.044194173824159216f   // 1/sqrt(512)

typedef __attribute__((ext_vector_type(8))) short short8;
typedef __attribute__((ext_vector_type(4))) float f32x4;

#define MFMA16(a, b, c) __builtin_amdgcn_mfma_f32_16x16x32_bf16((a), (b), (c), 0, 0, 0)

__device__ __forceinline__ void glds16(const void* g, void* l) {
  __builtin_amdgcn_global_load_lds(
      (const __attribute__((address_space(1))) void*)g,
      (__attribute__((address_space(3))) void*)l, 16, 0, 0);
}

__device__ __forceinline__ unsigned short f2bf(float f) {
  unsigned u = __float_as_uint(f);
  u += 0x7FFFu + ((u >> 16) & 1u);
  return (unsigned short)(u >> 16);
}

// ---------------------------------------------------------------------------
// fused fp32->bf16 convert for all three inputs (one launch)
__global__ __launch_bounds__(256) void convert3_kernel(
    const float* __restrict__ a, const float* __restrict__ b,
    const float* __restrict__ c, unsigned short* __restrict__ oa,
    unsigned short* __restrict__ ob, unsigned short* __restrict__ oc) {
  int i = blockIdx.x * 256 + threadIdx.x;  // grid covers 3*3145728 float4
  int which = i / 3145728;
  int off = i - which * 3145728;
  const float* s = (which == 0) ? a : (which == 1) ? b : c;
  unsigned short* d = (which == 0) ? oa : (which == 1) ? ob : oc;
  float4 v = ((const float4*)s)[off];
  ushort4 o;
  o.x = f2bf(v.x); o.y = f2bf(v.y); o.z = f2bf(v.z); o.w = f2bf(v.w);
  ((ushort4*)d)[off] = o;
}

__global__ void bias_build_kernel(const float* bqr, const float* bqi,
                                  const float* bkr, const float* bki,
                                  const float* bv, float* bq, float* bk,
                                  float* bvo) {
  int t = blockIdx.x * 256 + threadIdx.x;
  if (t < 512) { bq[t] = bqr[t]; bk[t] = bkr[t]; bvo[t] = bv[t]; }
  else if (t < 1024) { bq[t] = bqi[t - 512]; bk[t] = bki[t - 512]; }
}

// W [768][N] fp32 -> Wt[row_off + n][768] bf16
__global__ __launch_bounds__(256) void wtrans_kernel(
    const float* __restrict__ W, unsigned short* __restrict__ Wt, int N,
    int row_off) {
  __shared__ float t[32][33];
  int n0 = blockIdx.x * 32, k0 = blockIdx.y * 32;
  int tx = threadIdx.x & 31, ty = threadIdx.x >> 5;
#pragma unroll
  for (int r = 0; r < 4; ++r)
    t[ty + r * 8][tx] = W[(size_t)(k0 + ty + r * 8) * N + n0 + tx];
  __syncthreads();
#pragma unroll
  for (int r = 0; r < 4; ++r)
    Wt[(size_t)(row_off + n0 + ty + r * 8) * 768 + k0 + tx] =
        f2bf(t[tx][ty + r * 8]);
}

__global__ void init_kernel(float* lsum, float* coh) {
  int t = blockIdx.x * 256 + threadIdx.x;
  if (t < 16384) lsum[t] = 0.f;
  if (t == 0) *coh = 0.f;
}

// ---------------------------------------------------------------------------
// Projection GEMM (unchanged, known-good): Y[M,N] = Xb[M,768] @ Wt[N,768]^T + b
// ---------------------------------------------------------------------------
__global__ __launch_bounds__(256, 2) void proj_kernel(
    const unsigned short* __restrict__ Xb, const unsigned short* __restrict__ Wt,
    const float* __restrict__ bias, unsigned short* __restrict__ Y, int N,
    int vt_mode) {
  __shared__ char lds[32768];
  const int tid = threadIdx.x;
  const int lane = tid & 63, wid = tid >> 6;
  const int wi = wid >> 1, wj = wid & 1;
  const int m0 = blockIdx.y * 128, n0 = blockIdx.x * 128;
  const char* Xc = (const char*)Xb;
  const char* Wc = (const char*)Wt;

  f32x4 acc[4][4] = {};
  const int tile = wid >> 1;

  for (int s = 0; s < 12; ++s) {
    __syncthreads();
#pragma unroll
    for (int iss = 0; iss < 8; ++iss) {
      int gbase = wid * 512 + iss * 64;
      int loc = (gbase & 1023) + lane;
      int r = loc >> 3, blk = loc & 7;
      int sb = blk ^ (r & 7);
      const char* src = (tile == 0)
          ? Xc + (size_t)(m0 + r) * 1536 + s * 128 + sb * 16
          : Wc + (size_t)(n0 + r) * 1536 + s * 128 + sb * 16;
      glds16(src, lds + gbase * 16);
    }
    __syncthreads();
#pragma unroll
    for (int kk = 0; kk < 2; ++kk) {
      int blk = kk * 4 + (lane >> 4);
      short8 a[4];
#pragma unroll
      for (int i = 0; i < 4; ++i) {
        int row = wi * 64 + i * 16 + (lane & 15);
        a[i] = *(const short8*)(lds + row * 128 + ((blk ^ (row & 7)) << 4));
      }
#pragma unroll
      for (int j = 0; j < 4; ++j) {
        int row = wj * 64 + j * 16 + (lane & 15);
        short8 b = *(const short8*)(lds + 16384 + row * 128 +
                                    ((blk ^ (row & 7)) << 4));
#pragma unroll
        for (int i = 0; i < 4; ++i) acc[i][j] = MFMA16(a[i], b, acc[i][j]);
      }
    }
  }

#pragma unroll
  for (int j = 0; j < 4; ++j) {
    int n = n0 + wj * 64 + j * 16 + (lane & 15);
    float bn = bias[n];
    if (!vt_mode) {
#pragma unroll
      for (int i = 0; i < 4; ++i) {
        int mrow = m0 + wi * 64 + i * 16 + (lane >> 4) * 4;
#pragma unroll
        for (int r = 0; r < 4; ++r)
          Y[(size_t)(mrow + r) * N + n] = f2bf(acc[i][j][r] + bn);
      }
    } else {
#pragma unroll
      for (int i = 0; i < 4; ++i) {
        int mrow = m0 + wi * 64 + i * 16 + (lane >> 4) * 4;
        int b = mrow >> 11, key = mrow & 2047;
        ushort4 o;
        o.x = f2bf(acc[i][j][0] + bn);
        o.y = f2bf(acc[i][j][1] + bn);
        o.z = f2bf(acc[i][j][2] + bn);
        o.w = f2bf(acc[i][j][3] + bn);
        *(ushort4*)&Y[((size_t)b * 512 + n) * 2048 + key] = o;
      }
    }
  }
}

// ---------------------------------------------------------------------------
// Score kernel, 8-phase-style schedule with counted vmcnt (T2+T3+T4+T5).
// Tile 256x128 (q x k), 8 waves (4M x 2N), 512 threads.
// K half-space step = 32 cols (lo 32 + hi 32 interleaved per 128B LDS row).
// 3 LDS buffer sets x 48KB; prefetch 2 steps ahead; vmcnt(6) once per step.
// ---------------------------------------------------------------------------
__global__ __launch_bounds__(512, 2) void score_kernel(
    const unsigned short* __restrict__ Qcat,
    const unsigned short* __restrict__ Kcat, unsigned short* __restrict__ P,
    float* __restrict__ lsum, float* __restrict__ coh) {
  __shared__ char lds[147456];
  const int tid = threadIdx.x;
  const int lane = tid & 63, wid = tid >> 6;
  const int wm = wid >> 1;   // 0..3 : 64-row M quadrant
  const int wn = wid & 1;    // 0..1 : 64-col N half
  const int lr = lane & 15;
  const int lk = lane >> 4;
  const int l8 = lane >> 3, lb = lane & 7;

  const int id = blockIdx.x;
  const int batch = id & 7;          // batch pinned per XCD
  const int tile = id >> 3;          // 0..127
  const int q0 = (tile >> 4) << 8;   // 8 q-tiles of 256
  const int k0 = (tile & 15) << 7;   // 16 k-tiles of 128

  const char* Qc = (const char*)Qcat + ((size_t)batch * 2048 + q0) * 2048;
  const char* Kc = (const char*)Kcat + ((size_t)batch * 2048 + k0) * 2048;

  f32x4 accre[4][4] = {}, accim[4][4] = {};
  const short sg = (short)0x8000;
  const short8 SGN = {sg, sg, sg, sg, sg, sg, sg, sg};

  // one wave-load L in [0,48): L<32 -> QA rows 8L..8L+7 ; else KB rows.
  // LDS row = 128B = [lo 4 blocks | hi 4 blocks], XOR-swizzled by (row&7).
  auto stage = [&](int t, char* setbase, int L) {
    int row, sb;
    const char* src;
    if (L < 32) {
      row = (L << 3) + l8;
      sb = lb ^ (row & 7);
      src = Qc + (size_t)row * 2048 + t * 64 + (sb & 3) * 16 + (sb >> 2) * 1024;
    } else {
      row = ((L - 32) << 3) + l8;
      sb = lb ^ (row & 7);
      src = Kc + (size_t)row * 2048 + t * 64 + (sb & 3) * 16 + (sb >> 2) * 1024;
    }
    glds16(src, setbase + (L << 10));
  };

  // prologue: stage K-steps 0 and 1
#pragma unroll
  for (int u = 0; u < 6; ++u) stage(0, lds, wid * 6 + u);
#pragma unroll
  for (int u = 0; u < 6; ++u) stage(1, lds + 49152, wid * 6 + u);
  asm volatile("s_waitcnt vmcnt(6)" ::: "memory");  // set 0 complete (own loads)
  __builtin_amdgcn_s_barrier();                     // -> all waves' set 0 ready

  for (int t = 0; t < 16; ++t) {
    char* rbase = lds + (t % 3) * 49152;
    char* wbase = lds + ((t + 2) % 3) * 49152;
    short8 alo[4], ahi[4];
#pragma unroll
    for (int j = 0; j < 4; ++j) {
      if (j == 0) {
#pragma unroll
        for (int i = 0; i < 4; ++i) {
          int ar = wm * 64 + i * 16 + lr;
          const char* arow = rbase + ar * 128;
          alo[i] = *(const short8*)(arow + ((lk ^ (ar & 7)) << 4));
          ahi[i] = *(const short8*)(arow + (((4 + lk) ^ (ar & 7)) << 4));
        }
      }
      int br = wn * 64 + j * 16 + lr;
      const char* brow = rbase + 32768 + br * 128;
      short8 blo = *(const short8*)(brow + ((lk ^ (br & 7)) << 4));
      short8 bhi = *(const short8*)(brow + (((4 + lk) ^ (br & 7)) << 4));
      // prefetch shares for step t+2 (2,2,1,1 across the 4 phases)
      if (t < 14) {
        if (j == 0)      { stage(t + 2, wbase, wid * 6 + 0); stage(t + 2, wbase, wid * 6 + 1); }
        else if (j == 1) { stage(t + 2, wbase, wid * 6 + 2); stage(t + 2, wbase, wid * 6 + 3); }
        else if (j == 2) { stage(t + 2, wbase, wid * 6 + 4); }
        else             { stage(t + 2, wbase, wid * 6 + 5); }
      }
      __builtin_amdgcn_s_barrier();
      asm volatile("s_waitcnt lgkmcnt(0)" ::: "memory");
      __builtin_amdgcn_sched_barrier(0);
      __builtin_amdgcn_s_setprio(1);
      short8 bhin = bhi ^ SGN;
#pragma unroll
      for (int i = 0; i < 4; ++i) {
        accre[i][j] = MFMA16(alo[i], blo, accre[i][j]);
        accre[i][j] = MFMA16(ahi[i], bhi, accre[i][j]);
        accim[i][j] = MFMA16(ahi[i], blo, accim[i][j]);
        accim[i][j] = MFMA16(alo[i], bhin, accim[i][j]);
      }
      __builtin_amdgcn_s_setprio(0);
      if (j == 3) {
        // once per K-step, counted: t+1's loads done, t+2's (6) stay in flight
        if (t < 14)       asm volatile("s_waitcnt vmcnt(6)" ::: "memory");
        else if (t == 14) asm volatile("s_waitcnt vmcnt(0)" ::: "memory");
      }
      __builtin_amdgcn_s_barrier();
    }
  }
  __syncthreads();

  // epilogue: coherence, p=exp(mag*scale), P store, row sums
  float csum = 0.f;
  size_t prow_base = (size_t)batch * 2048;
  float rsum[16];
#pragma unroll
  for (int x = 0; x < 16; ++x) rsum[x] = 0.f;

#pragma unroll
  for (int i = 0; i < 4; ++i) {
#pragma unroll
    for (int r = 0; r < 4; ++r) {
      int row = q0 + wm * 64 + i * 16 + lk * 4 + r;
      unsigned short* prow = P + (prow_base + row) * 2048;
      float rs = 0.f;
#pragma unroll
      for (int j = 0; j < 4; ++j) {
        float re = accre[i][j][r], im = accim[i][j][r];
        csum += im * im;
        float p = __expf(sqrtf(re * re + im * im) * SCALE_);
        rs += p;
        prow[k0 + wn * 64 + j * 16 + lr] = f2bf(p);
      }
      rsum[i * 4 + r] = rs;
    }
  }
#pragma unroll
  for (int x = 0; x < 16; ++x) {
    float v = rsum[x];
    v += __shfl_xor(v, 1, 64);
    v += __shfl_xor(v, 2, 64);
    v += __shfl_xor(v, 4, 64);
    v += __shfl_xor(v, 8, 64);
    rsum[x] = v;
  }
  if (lr == 0) {
#pragma unroll
    for (int i = 0; i < 4; ++i)
#pragma unroll
      for (int r = 0; r < 4; ++r) {
        int row = q0 + wm * 64 + i * 16 + lk * 4 + r;
        atomicAdd(&lsum[prow_base + row], rsum[i * 4 + r]);
      }
  }
#pragma unroll
  for (int m = 1; m < 64; m <<= 1) csum += __shfl_xor(csum, m, 64);
  float* cred = (float*)lds;
  if (lane == 0) cred[wid] = csum;
  __syncthreads();
  if (tid == 0) {
    float s = 0.f;
#pragma unroll
    for (int w = 0; w < 8; ++w) s += cred[w];
    atomicAdd(coh, s);
  }
}

// ---------------------------------------------------------------------------
// PV GEMM (unchanged): out[b,i,n] = (sum_j P[b,i,j] * Vt[b,n,j]) / lsum[b,i]
// ---------------------------------------------------------------------------
__global__ __launch_bounds__(256, 2) void pv_kernel(
    const unsigned short* __restrict__ P, const unsigned short* __restrict__ Vt,
    const float* __restrict__ lsum, float* __restrict__ out) {
  __shared__ char lds[32768];
  const int tid = threadIdx.x;
  const int lane = tid & 63, wid = tid >> 6;
  const int wi = wid >> 1, wj = wid & 1;

  int id = blockIdx.x;
  int w = (id & 7) * 64 + (id >> 3);
  int batch = w >> 6, tilein = w & 63;
  int i0 = (tilein >> 2) * 128;
  int o0 = (tilein & 3) * 128;

  const char* Pc = (const char*)P + (size_t)batch * 2048 * 4096;
  const char* Vc = (const char*)Vt + (size_t)batch * 512 * 4096;

  f32x4 acc[4][4] = {};
  const int tile = wid >> 1;

  for (int s = 0; s < 32; ++s) {
    __syncthreads();
#pragma unroll
    for (int iss = 0; iss < 8; ++iss) {
      int gbase = wid * 512 + iss * 64;
      int loc = (gbase & 1023) + lane;
      int r = loc >> 3, blk = loc & 7;
      int sb = blk ^ (r & 7);
      const char* src = (tile == 0)
          ? Pc + (size_t)(i0 + r) * 4096 + s * 128 + sb * 16
          : Vc + (size_t)(o0 + r) * 4096 + s * 128 + sb * 16;
      glds16(src, lds + gbase * 16);
    }
    __syncthreads();
#pragma unroll
    for (int kk = 0; kk < 2; ++kk) {
      int blk = kk * 4 + (lane >> 4);
      short8 a[4];
#pragma unroll
      for (int i = 0; i < 4; ++i) {
        int row = wi * 64 + i * 16 + (lane & 15);
        a[i] = *(const short8*)(lds + row * 128 + ((blk ^ (row & 7)) << 4));
      }
#pragma unroll
      for (int j = 0; j < 4; ++j) {
        int row = wj * 64 + j * 16 + (lane & 15);
        short8 b = *(const short8*)(lds + 16384 + row * 128 +
                                    ((blk ^ (row & 7)) << 4));
#pragma unroll
        for (int i = 0; i < 4; ++i) acc[i][j] = MFMA16(a[i], b, acc[i][j]);
      }
    }
  }

#pragma unroll
  for (int i = 0; i < 4; ++i) {
    int mrow = i0 + wi * 64 + i * 16 + (lane >> 4) * 4;
    float linv[4];
#pragma unroll
    for (int r = 0; r < 4; ++r)
      linv[r] = 1.0f / lsum[(size_t)batch * 2048 + mrow + r];
#pragma unroll
    for (int j = 0; j < 4; ++j) {
      int n = o0 + wj * 64 + j * 16 + (lane & 15);
#pragma unroll
      for (int r = 0; r < 4; ++r)
        out[((size_t)batch * 2048 + mrow + r) * 512 + n] = acc[i][j][r] * linv[r];
    }
  }
}

__global__ void finalize_kernel(const float* __restrict__ coh,
                                const float* __restrict__ cw,
                                float* __restrict__ out_last) {
  *out_last = (*coh) * (1.0f / 33554432.0f) * (*cw);
}

// ---------------------------------------------------------------------------
extern "C" void kernel_launch(void* const* d_in, const int* in_sizes, int n_in,
                              void* d_out, int out_size, void* d_ws,
                              size_t ws_size, hipStream_t stream) {
  const float* query = (const float*)d_in[0];
  const float* key   = (const float*)d_in[1];
  const float* value = (const float*)d_in[2];
  const float* Wqr = (const float*)d_in[3];
  const float* bqr = (const float*)d_in[4];
  const float* Wqi = (const float*)d_in[5];
  const float* bqi = (const float*)d_in[6];
  const float* Wkr = (const float*)d_in[7];
  const float* bkr = (const float*)d_in[8];
  const float* Wki = (const float*)d_in[9];
  const float* bki = (const float*)d_in[10];
  const float* Wv  = (const float*)d_in[11];
  const float* bv  = (const float*)d_in[12];
  const float* cw  = (const float*)d_in[13];
  float* out = (float*)d_out;

  char* ws = (char*)d_ws;
  unsigned short* XQ   = (unsigned short*)(ws + 0);
  unsigned short* XK   = (unsigned short*)(ws + 25165824);
  unsigned short* XV   = (unsigned short*)(ws + 50331648);
  unsigned short* Pbuf = (unsigned short*)(ws + 0);          // overlays X after proj
  unsigned short* WTQ  = (unsigned short*)(ws + 75497472);
  unsigned short* WTK  = (unsigned short*)(ws + 77070336);
  unsigned short* WTV  = (unsigned short*)(ws + 78643200);
  float* BQ   = (float*)(ws + 79429632);
  float* BK   = (float*)(ws + 79433728);
  float* BV   = (float*)(ws + 79437824);
  unsigned short* QCAT = (unsigned short*)(ws + 79441920);
  unsigned short* KCAT = (unsigned short*)(ws + 112996352);
  unsigned short* VT   = (unsigned short*)(ws + 146550784);
  float* LSUM = (float*)(ws + 163328000);
  float* COH  = (float*)(ws + 163393536);
  if (ws_size < 163393600) return;

  convert3_kernel<<<36864, 256, 0, stream>>>(query, key, value, XQ, XK, XV);
  bias_build_kernel<<<4, 256, 0, stream>>>(bqr, bqi, bkr, bki, bv, BQ, BK, BV);
  wtrans_kernel<<<dim3(16, 24), 256, 0, stream>>>(Wqr, WTQ, 512, 0);
  wtrans_kernel<<<dim3(16, 24), 256, 0, stream>>>(Wqi, WTQ, 512, 512);
  wtrans_kernel<<<dim3(16, 24), 256, 0, stream>>>(Wkr, WTK, 512, 0);
  wtrans_kernel<<<dim3(16, 24), 256, 0, stream>>>(Wki, WTK, 512, 512);
  wtrans_kernel<<<dim3(16, 24), 256, 0, stream>>>(Wv, WTV, 512, 0);

  proj_kernel<<<dim3(8, 128), 256, 0, stream>>>(XQ, WTQ, BQ, QCAT, 1024, 0);
  proj_kernel<<<dim3(8, 128), 256, 0, stream>>>(XK, WTK, BK, KCAT, 1024, 0);
  proj_kernel<<<dim3(4, 128), 256, 0, stream>>>(XV, WTV, BV, VT, 512, 1);

  init_kernel<<<64, 256, 0, stream>>>(LSUM, COH);
  score_kernel<<<1024, 512, 0, stream>>>(QCAT, KCAT, Pbuf, LSUM, COH);
  pv_kernel<<<512, 256, 0, stream>>>(Pbuf, VT, LSUM, out);
  finalize_kernel<<<1, 1, 0, stream>>>(COH, cw, out + 8388608);
}